// Round 4
// baseline (2092.079 us; speedup 1.0000x reference)
//
#include <hip/hip_runtime.h>

typedef unsigned int uint_t;

#define BM 16
#define NBLK (65536 / BM)

__device__ inline float rsum32(float v) {
    #pragma unroll
    for (int o = 16; o > 0; o >>= 1) v += __shfl_xor(v, o, 32);
    return v;
}

// Fully-fused scalar actor, fp32 in/out: one block = 16 batch rows; no ws, no MFMA.
// LDS overlays (time-separated by __syncthreads):
//   xs  @ 0      (16*376*4 = 24064 B)   dead after h1 loop
//   h1s @ 24064  (16*400*4 = 25600 B)   dead after h2 loop
//   h2s @ 0      (16*300*4 = 19200 B)   overlays xs
//   hds @ 19200  (16*560*4 = 35840 B)   overlays h1s
// total 55040 B
__global__ __launch_bounds__(256)
void fused_actor(const float* __restrict__ x, const float* __restrict__ eps,
                 const float* __restrict__ W1, const float* __restrict__ b1,
                 const float* __restrict__ W2, const float* __restrict__ b2,
                 const float* __restrict__ Wmu, const float* __restrict__ bmu,
                 const float* __restrict__ Wlv, const float* __restrict__ blv,
                 const float* __restrict__ Wu, const float* __restrict__ bu,
                 const float* __restrict__ Ww, const float* __restrict__ bw,
                 const float* __restrict__ Wb, const float* __restrict__ bb,
                 float* __restrict__ out, int B)
{
    __shared__ __align__(16) char smem[55040];
    float* xs  = (float*)smem;                 // 16x376
    float* h1s = (float*)(smem + 24064);       // 16x400
    float* h2s = (float*)smem;                 // 16x300 (overlays xs)
    float* hds = (float*)(smem + 19200);       // 16x560 (overlays h1s)

    const int tid = threadIdx.x;
    const long row0 = (long)blockIdx.x * BM;

    // ---- load x tile (coalesced float4: 16 rows x 376 = 1504 float4) ----
    {
        const float4* src = reinterpret_cast<const float4*>(x + row0 * 376);
        float4* dst = reinterpret_cast<float4*>(xs);
        for (int i = tid; i < BM * 376 / 4; i += 256) dst[i] = src[i];
    }
    __syncthreads();

    // ---- h1 = relu(x @ W1 + b1), N=400 ----
    for (int n = tid; n < 400; n += 256) {
        float acc[BM];
        float bv = b1[n];
        #pragma unroll
        for (int r = 0; r < BM; ++r) acc[r] = bv;
        for (int k = 0; k < 376; k += 4) {
            float w0 = W1[(k + 0) * 400 + n];
            float w1 = W1[(k + 1) * 400 + n];
            float w2 = W1[(k + 2) * 400 + n];
            float w3 = W1[(k + 3) * 400 + n];
            #pragma unroll
            for (int r = 0; r < BM; ++r) {
                float4 xv = *reinterpret_cast<const float4*>(&xs[r * 376 + k]);
                acc[r] += xv.x * w0 + xv.y * w1 + xv.z * w2 + xv.w * w3;
            }
        }
        #pragma unroll
        for (int r = 0; r < BM; ++r)
            h1s[r * 400 + n] = fmaxf(acc[r], 0.f);
    }
    __syncthreads();   // xs dead

    // ---- h2 = relu(h1 @ W2 + b2), N=300 (h2s overlays xs) ----
    for (int n = tid; n < 300; n += 256) {
        float acc[BM];
        float bv = b2[n];
        #pragma unroll
        for (int r = 0; r < BM; ++r) acc[r] = bv;
        for (int k = 0; k < 400; k += 4) {
            float w0 = W2[(k + 0) * 300 + n];
            float w1 = W2[(k + 1) * 300 + n];
            float w2 = W2[(k + 2) * 300 + n];
            float w3 = W2[(k + 3) * 300 + n];
            #pragma unroll
            for (int r = 0; r < BM; ++r) {
                float4 hv = *reinterpret_cast<const float4*>(&h1s[r * 400 + k]);
                acc[r] += hv.x * w0 + hv.y * w1 + hv.z * w2 + hv.w * w3;
            }
        }
        #pragma unroll
        for (int r = 0; r < BM; ++r)
            h2s[r * 300 + n] = fmaxf(acc[r], 0.f);
    }
    __syncthreads();   // h1s dead; hds may overlay it

    // ---- heads: cols [0:17) mu, [17:34) lv, [34:289) u, [289:544) w, [544:559) b ----
    for (int n = tid; n < 559; n += 256) {
        const float* wp; int stride; float bv;
        if      (n < 17)  { wp = Wmu + n;         stride = 17;  bv = bmu[n]; }
        else if (n < 34)  { wp = Wlv + (n - 17);  stride = 17;  bv = blv[n - 17]; }
        else if (n < 289) { wp = Wu  + (n - 34);  stride = 255; bv = bu[n - 34]; }
        else if (n < 544) { wp = Ww  + (n - 289); stride = 255; bv = bw[n - 289]; }
        else              { wp = Wb  + (n - 544); stride = 15;  bv = bb[n - 544]; }
        float acc[BM];
        #pragma unroll
        for (int r = 0; r < BM; ++r) acc[r] = bv;
        for (int k = 0; k < 300; k += 4) {
            float w0 = wp[(k + 0) * stride];
            float w1 = wp[(k + 1) * stride];
            float w2 = wp[(k + 2) * stride];
            float w3 = wp[(k + 3) * stride];
            #pragma unroll
            for (int r = 0; r < BM; ++r) {
                float4 hv = *reinterpret_cast<const float4*>(&h2s[r * 300 + k]);
                acc[r] += hv.x * w0 + hv.y * w1 + hv.z * w2 + hv.w * w3;
            }
        }
        #pragma unroll
        for (int r = 0; r < BM; ++r)
            hds[r * 560 + n] = acc[r];
    }
    __syncthreads();

    // ---- planar flow + log-prob: 8 groups of 32 lanes, 2 passes over 16 rows ----
    const int lane = tid & 31;
    const bool on = lane < 17;
    #pragma unroll
    for (int pass = 0; pass < 2; ++pass) {
        const int r = pass * 8 + (tid >> 5);
        const long g = row0 + r;
        const float* hr = &hds[r * 560];

        float muv = on ? tanhf(hr[lane]) : 0.f;        // MAX_ACTION = 1
        float lvv = on ? tanhf(hr[17 + lane]) : 0.f;
        float ep  = on ? eps[g * 17 + lane] : 0.f;
        float z = muv + expf(lvv) * ep;                // rsample
        float lp = rsum32(on ? (-0.5f * ep * ep - lvv - 0.918938533f) : 0.f);

        float ldj = 0.f;
        #pragma unroll
        for (int k = 0; k < 15; ++k) {
            float uv  = on ? hr[34 + k * 17 + lane] : 0.f;
            float wvv = on ? hr[289 + k * 17 + lane] : 0.f;
            float bk  = hr[544 + k];
            float uw = rsum32(wvv * uv);
            float w2 = fmaxf(rsum32(wvv * wvv), 1e-20f);
            float sp = (uw > 15.f) ? uw : log1pf(expf(uw));  // softplus
            float m  = sp - 1.f;                             // -1 + softplus(w.u)
            float coef = (m - uw) / w2;
            float uh = uv + coef * wvv;                      // u_hat
            float t  = tanhf(rsum32(wvv * z) + bk);
            z += uh * t;
            float psi = m * (1.f - t * t);                   // psi^T u_hat == m analytically
            ldj += logf(fmaxf(fabsf(1.f + psi), 1e-30f));
        }
        float lpf = lp - ldj;
        if (on) out[g * 17 + lane] = z;
        if (lane == 0) {
            out[(long)B * 17 + g] = expf(lpf);
            out[(long)B * 18 + g] = lpf;
        }
    }
}

extern "C" void kernel_launch(void* const* d_in, const int* in_sizes, int n_in,
                              void* d_out, int out_size, void* d_ws, size_t ws_size,
                              hipStream_t stream)
{
    (void)in_sizes; (void)n_in; (void)d_ws; (void)ws_size; (void)out_size;
    fused_actor<<<NBLK, 256, 0, stream>>>(
        (const float*)d_in[0],  (const float*)d_in[1],
        (const float*)d_in[2],  (const float*)d_in[3],
        (const float*)d_in[4],  (const float*)d_in[5],
        (const float*)d_in[6],  (const float*)d_in[7],
        (const float*)d_in[8],  (const float*)d_in[9],
        (const float*)d_in[10], (const float*)d_in[11],
        (const float*)d_in[12], (const float*)d_in[13],
        (const float*)d_in[14], (const float*)d_in[15],
        (float*)d_out, 65536);
}

// Round 5
// 660.510 us; speedup vs baseline: 3.1674x; 3.1674x over previous
//
#include <hip/hip_runtime.h>

typedef unsigned short ushort_t;
typedef unsigned int uint_t;
typedef __bf16 bf16x8 __attribute__((ext_vector_type(8)));
typedef float f32x4 __attribute__((ext_vector_type(4)));

#define B_ROWS 65536

__device__ inline float bf2f(ushort_t u) {
    union { uint_t i; float f; } x; x.i = ((uint_t)u) << 16; return x.f;
}
__device__ inline ushort_t f2bf(float f) {
    uint_t u = __float_as_uint(f);
    return (ushort_t)((u + 0x7FFFu + ((u >> 16) & 1u)) >> 16);
}
__device__ inline uint_t pack2(float a, float b) {
    return (uint_t)f2bf(a) | ((uint_t)f2bf(b) << 16);
}

// ---------------------------------------------------------------------------
// cvt_kernel: fp32 -> bf16, vectorized (float4 -> 2x uint)
// ---------------------------------------------------------------------------
__global__ __launch_bounds__(256)
void cvt_kernel(const float* __restrict__ src, ushort_t* __restrict__ dst, long n4)
{
    long i = (long)blockIdx.x * 256 + threadIdx.x;
    if (i < n4) {
        float4 v = reinterpret_cast<const float4*>(src)[i];
        uint2 o; o.x = pack2(v.x, v.y); o.y = pack2(v.z, v.w);
        reinterpret_cast<uint2*>(dst)[i] = o;
    }
}

// ---------------------------------------------------------------------------
// pack_kernel: fp32 weights -> transposed/padded bf16 layouts + fp32 biasH.
//  W1T: (400 rows, 384 K)   W2T: (320 rows, 416 K)   WhT: (560 rows, 320 K)
//  head cols: [0:17) mu, [17:34) lv, [34:289) u, [289:544) w, [544:559) b, [559] pad
// ---------------------------------------------------------------------------
__global__ void pack_kernel(const float* __restrict__ W1, const float* __restrict__ W2,
                            const float* __restrict__ Wmu, const float* __restrict__ Wlv,
                            const float* __restrict__ Wu, const float* __restrict__ Ww,
                            const float* __restrict__ Wb,
                            const float* __restrict__ bmu, const float* __restrict__ blv,
                            const float* __restrict__ bu, const float* __restrict__ bw,
                            const float* __restrict__ bb,
                            ushort_t* __restrict__ W1T, ushort_t* __restrict__ W2T,
                            ushort_t* __restrict__ WhT, float* __restrict__ biasH)
{
    int i = blockIdx.x * 256 + threadIdx.x;
    const int s1 = 400 * 384, s2 = 320 * 416, s3 = 560 * 320;
    if (i < s1) {
        int n = i / 384, k = i - n * 384;
        W1T[i] = (k < 376) ? f2bf(W1[k * 400 + n]) : (ushort_t)0;
    } else if (i < s1 + s2) {
        int j = i - s1; int n = j / 416, k = j - n * 416;
        W2T[j] = (n < 300 && k < 400) ? f2bf(W2[k * 300 + n]) : (ushort_t)0;
    } else if (i < s1 + s2 + s3) {
        int j = i - s1 - s2; int n = j / 320, k = j - n * 320;
        float v = 0.f;
        if (k < 300) {
            if      (n < 17)  v = Wmu[k * 17 + n];
            else if (n < 34)  v = Wlv[k * 17 + (n - 17)];
            else if (n < 289) v = Wu[k * 255 + (n - 34)];
            else if (n < 544) v = Ww[k * 255 + (n - 289)];
            else if (n < 559) v = Wb[k * 15 + (n - 544)];
        }
        WhT[j] = f2bf(v);
    } else {
        int j = i - s1 - s2 - s3;
        if (j < 560) {
            float v = 0.f;
            if      (j < 17)  v = bmu[j];
            else if (j < 34)  v = blv[j - 17];
            else if (j < 289) v = bu[j - 34];
            else if (j < 544) v = bw[j - 289];
            else if (j < 559) v = bb[j - 544];
            biasH[j] = v;
        }
    }
}

// ---------------------------------------------------------------------------
// gemm_kernel: C(M x ldc, bf16) = act(A(M x Ka, bf16) @ Bt^T + bias_f32)
// BM=128, BN=80, BK=32; 256 threads = 4 waves; mfma_f32_16x16x32_bf16.
// LDS row stride 40 bf16 (80 B): 16B frag reads hit distinct bank groups (free).
// ---------------------------------------------------------------------------
template<bool RELU>
__global__ __launch_bounds__(256)
void gemm_kernel(const ushort_t* __restrict__ A, const ushort_t* __restrict__ Bt,
                 const float* __restrict__ bias, ushort_t* __restrict__ C,
                 int lda, int ldbt, int ldc, int Ka, int kIters, int Nreal)
{
    __shared__ ushort_t As[128 * 40];
    __shared__ ushort_t Bs[80 * 40];
    const int tid = threadIdx.x;
    const int lane = tid & 63, wv = tid >> 6;
    const int q = lane >> 4, l16 = lane & 15;
    const int n0 = blockIdx.x * 80;
    const long row0 = (long)blockIdx.y * 128;

    f32x4 acc[2][5];
    #pragma unroll
    for (int r = 0; r < 2; ++r)
        #pragma unroll
        for (int c = 0; c < 5; ++c)
            acc[r][c] = (f32x4){0.f, 0.f, 0.f, 0.f};

    for (int kt = 0; kt < kIters; ++kt) {
        const int k0 = kt * 32;
        #pragma unroll
        for (int i = 0; i < 2; ++i) {
            int u = tid + i * 256;
            int row = u >> 2, ku = u & 3;
            int k = k0 + ku * 8;
            uint4 v = {0u, 0u, 0u, 0u};
            if (k + 8 <= Ka)
                v = *reinterpret_cast<const uint4*>(A + (row0 + row) * (long)lda + k);
            *reinterpret_cast<uint4*>(&As[row * 40 + ku * 8]) = v;
        }
        {
            int row = tid >> 2, ku = tid & 3;
            *reinterpret_cast<uint4*>(&Bs[row * 40 + ku * 8]) =
                *reinterpret_cast<const uint4*>(Bt + (size_t)(n0 + row) * ldbt + k0 + ku * 8);
            if (tid < 64) {
                int u = 256 + tid; int row2 = u >> 2, ku2 = u & 3;
                *reinterpret_cast<uint4*>(&Bs[row2 * 40 + ku2 * 8]) =
                    *reinterpret_cast<const uint4*>(Bt + (size_t)(n0 + row2) * ldbt + k0 + ku2 * 8);
            }
        }
        __syncthreads();

        bf16x8 af[2], bfr[5];
        #pragma unroll
        for (int r = 0; r < 2; ++r) {
            uint4 v = *reinterpret_cast<const uint4*>(&As[(wv * 32 + r * 16 + l16) * 40 + q * 8]);
            af[r] = __builtin_bit_cast(bf16x8, v);
        }
        #pragma unroll
        for (int c = 0; c < 5; ++c) {
            uint4 v = *reinterpret_cast<const uint4*>(&Bs[(c * 16 + l16) * 40 + q * 8]);
            bfr[c] = __builtin_bit_cast(bf16x8, v);
        }
        #pragma unroll
        for (int r = 0; r < 2; ++r)
            #pragma unroll
            for (int c = 0; c < 5; ++c)
                acc[r][c] = __builtin_amdgcn_mfma_f32_16x16x32_bf16(af[r], bfr[c], acc[r][c], 0, 0, 0);
        __syncthreads();
    }

    #pragma unroll
    for (int r = 0; r < 2; ++r) {
        #pragma unroll
        for (int c = 0; c < 5; ++c) {
            int n = n0 + c * 16 + l16;
            float bv = (n < Nreal) ? bias[n] : 0.f;
            #pragma unroll
            for (int reg = 0; reg < 4; ++reg) {
                long m = row0 + wv * 32 + r * 16 + q * 4 + reg;
                float v = acc[r][c][reg] + bv;
                if (RELU) v = fmaxf(v, 0.f);
                if (n >= Nreal) v = 0.f;
                C[m * (long)ldc + n] = f2bf(v);
            }
        }
    }
}

// ---------------------------------------------------------------------------
// flow_kernel: one wave per batch row (chunk-local). heads row (bf16, 560):
//  [0:17) mu_raw, [17:34) lv_raw, [34:289) u, [289:544) w, [544:559) b, [559] pad
// eps fp32, out fp32.
// ---------------------------------------------------------------------------
__device__ inline float rsum32(float v) {
    #pragma unroll
    for (int o = 16; o > 0; o >>= 1) v += __shfl_xor(v, o, 32);
    return v;
}

__global__ __launch_bounds__(256)
void flow_kernel(const ushort_t* __restrict__ heads, const float* __restrict__ eps,
                 float* __restrict__ out, int rowBase, int B)
{
    __shared__ uint4 sbuf[4][70];
    const int wv = threadIdx.x >> 6, lane = threadIdx.x & 63;
    const long row = (long)blockIdx.x * 4 + wv;     // chunk-local
    const long g = rowBase + row;                   // global batch row
    const uint4* src = reinterpret_cast<const uint4*>(heads + row * 560);
    sbuf[wv][lane] = src[lane];
    if (lane < 6) sbuf[wv][64 + lane] = src[64 + lane];
    __syncthreads();
    const ushort_t* sr = reinterpret_cast<const ushort_t*>(sbuf[wv]);

    const bool on = lane < 17;
    float muv = on ? tanhf(bf2f(sr[lane])) : 0.f;          // MAX_ACTION = 1
    float lvv = on ? tanhf(bf2f(sr[17 + lane])) : 0.f;
    float ep  = on ? eps[g * 17 + lane] : 0.f;
    float z = muv + expf(lvv) * ep;                        // rsample
    float lp = rsum32(on ? (-0.5f * ep * ep - lvv - 0.918938533f) : 0.f);

    float ldj = 0.f;
    #pragma unroll
    for (int k = 0; k < 15; ++k) {
        float uv  = on ? bf2f(sr[34 + k * 17 + lane]) : 0.f;
        float wvv = on ? bf2f(sr[289 + k * 17 + lane]) : 0.f;
        float bk  = bf2f(sr[544 + k]);
        float uw = rsum32(wvv * uv);
        float w2 = fmaxf(rsum32(wvv * wvv), 1e-20f);
        float sp = (uw > 15.f) ? uw : log1pf(expf(uw));    // softplus
        float m  = sp - 1.f;                               // -1 + softplus(w.u)
        float coef = (m - uw) / w2;
        float uh = uv + coef * wvv;                        // u_hat
        float t  = tanhf(rsum32(wvv * z) + bk);
        z += uh * t;
        float psi = m * (1.f - t * t);                     // psi^T u_hat == m analytically
        ldj += logf(fmaxf(fabsf(1.f + psi), 1e-30f));
    }
    float lpf = lp - ldj;
    if (on) out[g * 17 + lane] = z;
    if (lane == 0) {
        out[(long)B * 17 + g] = expf(lpf);
        out[(long)B * 18 + g] = lpf;
    }
}

// ---------------------------------------------------------------------------
extern "C" void kernel_launch(void* const* d_in, const int* in_sizes, int n_in,
                              void* d_out, int out_size, void* d_ws, size_t ws_size,
                              hipStream_t stream)
{
    const float* x   = (const float*)d_in[0];
    const float* eps = (const float*)d_in[1];
    float* out = (float*)d_out;

    // Weight pack sizes (bf16 elems)
    const int s1 = 400 * 384, s2 = 320 * 416, s3 = 560 * 320;

    // ws layout per chunk of Mc rows (bf16 elems unless noted):
    //   region1: Mc*560  (h1 [ldc 400], later heads [ldc 560])
    //   region2: Mc*376  (x_bf16 [lda 376], later h2 [ldc 320])
    //   W1T s1 | W2T s2 | WhT s3 | biasH 560 f32
    const size_t fixedBytes = ((size_t)s1 + s2 + s3) * 2 + 560 * 4;
    int Mc = 1024;
    {
        const int cand[6] = {65536, 32768, 16384, 8192, 4096, 2048};
        for (int i = 0; i < 6; ++i) {
            size_t req = (size_t)cand[i] * (560 + 376) * 2 + fixedBytes;
            if (req <= ws_size) { Mc = cand[i]; break; }
        }
    }

    ushort_t* region1 = (ushort_t*)d_ws;
    ushort_t* region2 = region1 + (size_t)Mc * 560;
    ushort_t* W1T = region2 + (size_t)Mc * 376;
    ushort_t* W2T = W1T + s1;
    ushort_t* WhT = W2T + s2;
    float* biasH  = (float*)(WhT + s3);

    const int packN = s1 + s2 + s3 + 560;
    pack_kernel<<<(packN + 255) / 256, 256, 0, stream>>>(
        (const float*)d_in[2],  (const float*)d_in[4],
        (const float*)d_in[6],  (const float*)d_in[8],
        (const float*)d_in[10], (const float*)d_in[12], (const float*)d_in[14],
        (const float*)d_in[7],  (const float*)d_in[9],
        (const float*)d_in[11], (const float*)d_in[13], (const float*)d_in[15],
        W1T, W2T, WhT, biasH);

    const float* b1 = (const float*)d_in[3];
    const float* b2 = (const float*)d_in[5];

    const int nChunks = B_ROWS / Mc;
    const long n4 = (long)Mc * 376 / 4;
    for (int c = 0; c < nChunks; ++c) {
        const float* xc = x + (size_t)c * Mc * 376;
        // C0: x chunk fp32 -> bf16 into region2
        cvt_kernel<<<(n4 + 255) / 256, 256, 0, stream>>>(xc, region2, n4);
        // K1: h1 = relu(x @ W1 + b1)   M=Mc K=376 N=400
        gemm_kernel<true><<<dim3(5, Mc / 128), 256, 0, stream>>>(
            region2, W1T, b1, region1, 376, 384, 400, 376, 12, 400);
        // K2: h2 = relu(h1 @ W2 + b2)  M=Mc K=400 N=300 (stored 320-wide)
        gemm_kernel<true><<<dim3(4, Mc / 128), 256, 0, stream>>>(
            region1, W2T, b2, region2, 400, 416, 320, 400, 13, 300);
        // K3: heads = h2 @ Whead + biasH  M=Mc K=320 N=559 (stored 560-wide)
        gemm_kernel<false><<<dim3(7, Mc / 128), 256, 0, stream>>>(
            region2, WhT, biasH, region1, 320, 320, 560, 320, 10, 559);
        // K4: planar flow + log-prob epilogue
        flow_kernel<<<Mc / 4, 256, 0, stream>>>(region1, eps + (size_t)c * Mc * 17,
                                                out, c * Mc, B_ROWS);
    }
}

// Round 6
// 453.904 us; speedup vs baseline: 4.6091x; 1.4552x over previous
//
#include <hip/hip_runtime.h>

typedef unsigned short ushort_t;
typedef unsigned int uint_t;
typedef __bf16 bf16x8 __attribute__((ext_vector_type(8)));
typedef float f32x4 __attribute__((ext_vector_type(4)));

#define B_ROWS 65536

__device__ inline float bf2f(ushort_t u) {
    union { uint_t i; float f; } x; x.i = ((uint_t)u) << 16; return x.f;
}
__device__ inline ushort_t f2bf(float f) {
    uint_t u = __float_as_uint(f);
    return (ushort_t)((u + 0x7FFFu + ((u >> 16) & 1u)) >> 16);
}
__device__ inline uint_t pack2(float a, float b) {
    return (uint_t)f2bf(a) | ((uint_t)f2bf(b) << 16);
}
__device__ inline float fast_tanh(float x) {
    // (e^{2x}-1)/(e^{2x}+1) in cancellation-safe form; saturates correctly at +-inf
    float e = __expf(2.f * x);
    return 1.f - 2.f / (e + 1.f);
}

// ---------------------------------------------------------------------------
// cvt_kernel: fp32 -> bf16, vectorized (float4 -> 2x uint)
// ---------------------------------------------------------------------------
__global__ __launch_bounds__(256)
void cvt_kernel(const float* __restrict__ src, ushort_t* __restrict__ dst, long n4)
{
    long i = (long)blockIdx.x * 256 + threadIdx.x;
    if (i < n4) {
        float4 v = reinterpret_cast<const float4*>(src)[i];
        uint2 o; o.x = pack2(v.x, v.y); o.y = pack2(v.z, v.w);
        reinterpret_cast<uint2*>(dst)[i] = o;
    }
}

// ---------------------------------------------------------------------------
// pack_kernel: fp32 weights -> transposed/padded bf16 layouts + fp32 biasH.
//  W1T: (400 rows, 384 K)   W2T: (320 rows, 416 K)   WhT: (560 rows, 320 K)
//  head cols: [0:17) mu, [17:34) lv, [34:289) u, [289:544) w, [544:559) b, [559] pad
// ---------------------------------------------------------------------------
__global__ void pack_kernel(const float* __restrict__ W1, const float* __restrict__ W2,
                            const float* __restrict__ Wmu, const float* __restrict__ Wlv,
                            const float* __restrict__ Wu, const float* __restrict__ Ww,
                            const float* __restrict__ Wb,
                            const float* __restrict__ bmu, const float* __restrict__ blv,
                            const float* __restrict__ bu, const float* __restrict__ bw,
                            const float* __restrict__ bb,
                            ushort_t* __restrict__ W1T, ushort_t* __restrict__ W2T,
                            ushort_t* __restrict__ WhT, float* __restrict__ biasH)
{
    int i = blockIdx.x * 256 + threadIdx.x;
    const int s1 = 400 * 384, s2 = 320 * 416, s3 = 560 * 320;
    if (i < s1) {
        int n = i / 384, k = i - n * 384;
        W1T[i] = (k < 376) ? f2bf(W1[k * 400 + n]) : (ushort_t)0;
    } else if (i < s1 + s2) {
        int j = i - s1; int n = j / 416, k = j - n * 416;
        W2T[j] = (n < 300 && k < 400) ? f2bf(W2[k * 300 + n]) : (ushort_t)0;
    } else if (i < s1 + s2 + s3) {
        int j = i - s1 - s2; int n = j / 320, k = j - n * 320;
        float v = 0.f;
        if (k < 300) {
            if      (n < 17)  v = Wmu[k * 17 + n];
            else if (n < 34)  v = Wlv[k * 17 + (n - 17)];
            else if (n < 289) v = Wu[k * 255 + (n - 34)];
            else if (n < 544) v = Ww[k * 255 + (n - 289)];
            else if (n < 559) v = Wb[k * 15 + (n - 544)];
        }
        WhT[j] = f2bf(v);
    } else {
        int j = i - s1 - s2 - s3;
        if (j < 560) {
            float v = 0.f;
            if      (j < 17)  v = bmu[j];
            else if (j < 34)  v = blv[j - 17];
            else if (j < 289) v = bu[j - 34];
            else if (j < 544) v = bw[j - 289];
            else if (j < 559) v = bb[j - 544];
            biasH[j] = v;
        }
    }
}

// ---------------------------------------------------------------------------
// gemm_kernel: C(M x ldc, bf16) = act(A(M x Ka, bf16) @ Bt^T + bias_f32)
// BM=128, BN=80, BK=32; 256 threads = 4 waves; mfma_f32_16x16x32_bf16.
// ---------------------------------------------------------------------------
template<bool RELU>
__global__ __launch_bounds__(256)
void gemm_kernel(const ushort_t* __restrict__ A, const ushort_t* __restrict__ Bt,
                 const float* __restrict__ bias, ushort_t* __restrict__ C,
                 int lda, int ldbt, int ldc, int Ka, int kIters, int Nreal)
{
    __shared__ ushort_t As[128 * 40];
    __shared__ ushort_t Bs[80 * 40];
    const int tid = threadIdx.x;
    const int lane = tid & 63, wv = tid >> 6;
    const int q = lane >> 4, l16 = lane & 15;
    const int n0 = blockIdx.x * 80;
    const long row0 = (long)blockIdx.y * 128;

    f32x4 acc[2][5];
    #pragma unroll
    for (int r = 0; r < 2; ++r)
        #pragma unroll
        for (int c = 0; c < 5; ++c)
            acc[r][c] = (f32x4){0.f, 0.f, 0.f, 0.f};

    for (int kt = 0; kt < kIters; ++kt) {
        const int k0 = kt * 32;
        #pragma unroll
        for (int i = 0; i < 2; ++i) {
            int u = tid + i * 256;
            int row = u >> 2, ku = u & 3;
            int k = k0 + ku * 8;
            uint4 v = {0u, 0u, 0u, 0u};
            if (k + 8 <= Ka)
                v = *reinterpret_cast<const uint4*>(A + (row0 + row) * (long)lda + k);
            *reinterpret_cast<uint4*>(&As[row * 40 + ku * 8]) = v;
        }
        {
            int row = tid >> 2, ku = tid & 3;
            *reinterpret_cast<uint4*>(&Bs[row * 40 + ku * 8]) =
                *reinterpret_cast<const uint4*>(Bt + (size_t)(n0 + row) * ldbt + k0 + ku * 8);
            if (tid < 64) {
                int u = 256 + tid; int row2 = u >> 2, ku2 = u & 3;
                *reinterpret_cast<uint4*>(&Bs[row2 * 40 + ku2 * 8]) =
                    *reinterpret_cast<const uint4*>(Bt + (size_t)(n0 + row2) * ldbt + k0 + ku2 * 8);
            }
        }
        __syncthreads();

        bf16x8 af[2], bfr[5];
        #pragma unroll
        for (int r = 0; r < 2; ++r) {
            uint4 v = *reinterpret_cast<const uint4*>(&As[(wv * 32 + r * 16 + l16) * 40 + q * 8]);
            af[r] = __builtin_bit_cast(bf16x8, v);
        }
        #pragma unroll
        for (int c = 0; c < 5; ++c) {
            uint4 v = *reinterpret_cast<const uint4*>(&Bs[(c * 16 + l16) * 40 + q * 8]);
            bfr[c] = __builtin_bit_cast(bf16x8, v);
        }
        #pragma unroll
        for (int r = 0; r < 2; ++r)
            #pragma unroll
            for (int c = 0; c < 5; ++c)
                acc[r][c] = __builtin_amdgcn_mfma_f32_16x16x32_bf16(af[r], bfr[c], acc[r][c], 0, 0, 0);
        __syncthreads();
    }

    #pragma unroll
    for (int r = 0; r < 2; ++r) {
        #pragma unroll
        for (int c = 0; c < 5; ++c) {
            int n = n0 + c * 16 + l16;
            float bv = (n < Nreal) ? bias[n] : 0.f;
            #pragma unroll
            for (int reg = 0; reg < 4; ++reg) {
                long m = row0 + wv * 32 + r * 16 + q * 4 + reg;
                float v = acc[r][c][reg] + bv;
                if (RELU) v = fmaxf(v, 0.f);
                if (n >= Nreal) v = 0.f;
                C[m * (long)ldc + n] = f2bf(v);
            }
        }
    }
}

// ---------------------------------------------------------------------------
// flow_kernel v2: ONE THREAD PER ROW. Block = 128 threads = 128 rows.
// Per-k slices staged cooperatively into transposed LDS [i][row] (stride 129,
// conflict-free). z/u/w in registers; fast HW transcendentals; no shuffles.
// ---------------------------------------------------------------------------
#define FR 128   // rows per flow block

__global__ __launch_bounds__(FR)
void flow_kernel(const ushort_t* __restrict__ heads, const float* __restrict__ eps,
                 float* __restrict__ out, int rowBase, int B)
{
    __shared__ float lu[17 * (FR + 1)];
    __shared__ float lw[17 * (FR + 1)];
    __shared__ float le[17 * (FR + 1)];
    __shared__ float lb[FR];
    const int tid = threadIdx.x;
    const long row0 = (long)blockIdx.x * FR;          // chunk-local
    const ushort_t* hbase = heads + row0 * 560;

    // stage mu -> lu, lv -> lw (transposed); eps -> le (coalesced in, transposed out)
    for (int idx = tid; idx < FR * 17; idx += FR) {
        int r = idx / 17, i = idx - r * 17;
        lu[i * (FR + 1) + r] = bf2f(hbase[(long)r * 560 + i]);
        lw[i * (FR + 1) + r] = bf2f(hbase[(long)r * 560 + 17 + i]);
        le[i * (FR + 1) + r] = eps[row0 * 17 + idx];
    }
    __syncthreads();

    float z[17];
    float lp = 0.f;
    #pragma unroll
    for (int i = 0; i < 17; ++i) {
        float mu = fast_tanh(lu[i * (FR + 1) + tid]);
        float lv = fast_tanh(lw[i * (FR + 1) + tid]);
        float ep = le[i * (FR + 1) + tid];
        z[i] = mu + __expf(lv) * ep;
        lp += -0.5f * ep * ep - lv - 0.918938533f;
    }

    float ldj = 0.f;
    for (int k = 0; k < 15; ++k) {
        __syncthreads();   // previous reads done before overwrite
        for (int idx = tid; idx < FR * 17; idx += FR) {
            int r = idx / 17, i = idx - r * 17;
            long rb = (long)r * 560;
            lu[i * (FR + 1) + r] = bf2f(hbase[rb + 34 + k * 17 + i]);
            lw[i * (FR + 1) + r] = bf2f(hbase[rb + 289 + k * 17 + i]);
        }
        lb[tid] = bf2f(hbase[(long)tid * 560 + 544 + k]);
        __syncthreads();

        float u[17], w[17];
        float uw = 0.f, w2 = 0.f, wz = 0.f;
        #pragma unroll
        for (int i = 0; i < 17; ++i) {
            u[i] = lu[i * (FR + 1) + tid];
            w[i] = lw[i * (FR + 1) + tid];
            uw += w[i] * u[i];
            w2 += w[i] * w[i];
            wz += w[i] * z[i];
        }
        float sp = (uw > 15.f) ? uw : __logf(1.f + __expf(uw));  // softplus
        float m = sp - 1.f;                                      // -1 + softplus(w.u)
        float coef = (m - uw) / fmaxf(w2, 1e-20f);
        float t = fast_tanh(wz + lb[tid]);
        #pragma unroll
        for (int i = 0; i < 17; ++i)
            z[i] += (u[i] + coef * w[i]) * t;
        float psi = m * (1.f - t * t);                           // psi^T u_hat == m
        ldj += __logf(fmaxf(fabsf(1.f + psi), 1e-30f));
    }

    const long g = rowBase + row0 + tid;
    #pragma unroll
    for (int i = 0; i < 17; ++i) out[g * 17 + i] = z[i];
    float lpf = lp - ldj;
    out[(long)B * 17 + g] = __expf(lpf);
    out[(long)B * 18 + g] = lpf;
}

// ---------------------------------------------------------------------------
extern "C" void kernel_launch(void* const* d_in, const int* in_sizes, int n_in,
                              void* d_out, int out_size, void* d_ws, size_t ws_size,
                              hipStream_t stream)
{
    const float* x   = (const float*)d_in[0];
    const float* eps = (const float*)d_in[1];
    float* out = (float*)d_out;

    const int s1 = 400 * 384, s2 = 320 * 416, s3 = 560 * 320;
    const size_t fixedBytes = ((size_t)s1 + s2 + s3) * 2 + 560 * 4;
    int Mc = 1024;
    {
        const int cand[6] = {65536, 32768, 16384, 8192, 4096, 2048};
        for (int i = 0; i < 6; ++i) {
            size_t req = (size_t)cand[i] * (560 + 376) * 2 + fixedBytes;
            if (req <= ws_size) { Mc = cand[i]; break; }
        }
    }

    ushort_t* region1 = (ushort_t*)d_ws;                 // Mc*560: h1, later heads
    ushort_t* region2 = region1 + (size_t)Mc * 560;      // Mc*376: x_bf16, later h2
    ushort_t* W1T = region2 + (size_t)Mc * 376;
    ushort_t* W2T = W1T + s1;
    ushort_t* WhT = W2T + s2;
    float* biasH  = (float*)(WhT + s3);

    const int packN = s1 + s2 + s3 + 560;
    pack_kernel<<<(packN + 255) / 256, 256, 0, stream>>>(
        (const float*)d_in[2],  (const float*)d_in[4],
        (const float*)d_in[6],  (const float*)d_in[8],
        (const float*)d_in[10], (const float*)d_in[12], (const float*)d_in[14],
        (const float*)d_in[7],  (const float*)d_in[9],
        (const float*)d_in[11], (const float*)d_in[13], (const float*)d_in[15],
        W1T, W2T, WhT, biasH);

    const float* b1 = (const float*)d_in[3];
    const float* b2 = (const float*)d_in[5];

    const int nChunks = B_ROWS / Mc;
    const long n4 = (long)Mc * 376 / 4;
    for (int c = 0; c < nChunks; ++c) {
        const float* xc = x + (size_t)c * Mc * 376;
        cvt_kernel<<<(n4 + 255) / 256, 256, 0, stream>>>(xc, region2, n4);
        // K1: h1 = relu(x @ W1 + b1)   M=Mc K=376 N=400
        gemm_kernel<true><<<dim3(5, Mc / 128), 256, 0, stream>>>(
            region2, W1T, b1, region1, 376, 384, 400, 376, 12, 400);
        // K2: h2 = relu(h1 @ W2 + b2)  M=Mc K=400 N=300 (stored 320-wide)
        gemm_kernel<true><<<dim3(4, Mc / 128), 256, 0, stream>>>(
            region1, W2T, b2, region2, 400, 416, 320, 400, 13, 300);
        // K3: heads = h2 @ Whead + biasH  M=Mc K=320 N=559 (stored 560-wide)
        gemm_kernel<false><<<dim3(7, Mc / 128), 256, 0, stream>>>(
            region2, WhT, biasH, region1, 320, 320, 560, 320, 10, 559);
        // K4: planar flow + log-prob epilogue (one thread per row)
        flow_kernel<<<Mc / FR, FR, 0, stream>>>(region1, eps + (size_t)c * Mc * 17,
                                                out, c * Mc, B_ROWS);
    }
}

// Round 7
// 375.795 us; speedup vs baseline: 5.5671x; 1.2078x over previous
//
#include <hip/hip_runtime.h>

typedef unsigned short ushort_t;
typedef unsigned int uint_t;
typedef __bf16 bf16x8 __attribute__((ext_vector_type(8)));
typedef float f32x4 __attribute__((ext_vector_type(4)));

#define B_ROWS 65536

// Tile geometry: one MFMA tile = 16 rows x 32 k of bf16 = 1024 B = 512 ushorts.
// Unit l (0..63) within a tile <-> (row = l&15, k = (l>>4)*8 .. +8).
#define KT1 12    // x' k-tiles   (K 376 -> 384)
#define NT1 30    // K1 n-tiles   (N 400 -> 480)
#define KTC1 15   // h1' k-tiles  (480/32)
#define KI2 13    // K2 k-iters   (K 400 -> 416)
#define NT2 20    // K2 n-tiles   (N 320)
#define KTC2 10   // h2' k-tiles  (320/32)
#define KI3 10    // K3 k-iters   (320/32)
#define NT3 40    // K3 n-tiles   (N 560 -> 640)
#define LDC3 640

#define SZ1 (NT1 * KT1 * 512)
#define SZ2 (NT2 * KI2 * 512)
#define SZ3 (NT3 * KI3 * 512)

__device__ inline float bf2f(ushort_t u) {
    union { uint_t i; float f; } x; x.i = ((uint_t)u) << 16; return x.f;
}
__device__ inline ushort_t f2bf(float f) {
    uint_t u = __float_as_uint(f);
    return (ushort_t)((u + 0x7FFFu + ((u >> 16) & 1u)) >> 16);
}
__device__ inline uint_t pack2(float a, float b) {
    return (uint_t)f2bf(a) | ((uint_t)f2bf(b) << 16);
}
__device__ inline float fast_tanh(float x) {
    float e = __expf(2.f * x);
    return 1.f - 2.f / (e + 1.f);
}
// async global->LDS, 16 B per lane; LDS dest = wave-uniform base + lane*16
__device__ inline void gl2lds16(const ushort_t* g, ushort_t* l) {
    __builtin_amdgcn_global_load_lds(
        (const __attribute__((address_space(1))) uint_t*)g,
        (__attribute__((address_space(3))) uint_t*)l, 16, 0, 0);
}

// ---------------------------------------------------------------------------
// pack_kernel: fp32 weights -> MFMA-tile-order bf16 + zero-padded fp32 biases.
//  W1t: 30 ntiles x 12 ktiles   (real n<400, k<376)
//  W2t: 20 ntiles x 13 ktiles   (real n<300, k<400)
//  Wht: 40 ntiles x 10 ktiles   (real n<559 per concat map, k<300)
//  head cols: [0:17) mu, [17:34) lv, [34:289) u, [289:544) w, [544:559) b
// ---------------------------------------------------------------------------
__global__ void pack_kernel(const float* __restrict__ W1, const float* __restrict__ W2,
                            const float* __restrict__ Wmu, const float* __restrict__ Wlv,
                            const float* __restrict__ Wu, const float* __restrict__ Ww,
                            const float* __restrict__ Wb,
                            const float* __restrict__ b1, const float* __restrict__ b2,
                            const float* __restrict__ bmu, const float* __restrict__ blv,
                            const float* __restrict__ bu, const float* __restrict__ bw,
                            const float* __restrict__ bb,
                            ushort_t* __restrict__ W1t, ushort_t* __restrict__ W2t,
                            ushort_t* __restrict__ Wht,
                            float* __restrict__ b1p, float* __restrict__ b2p,
                            float* __restrict__ bHp)
{
    int i = blockIdx.x * 256 + threadIdx.x;
    if (i < SZ1) {
        int t = i >> 9, pos = i & 511;
        int l = pos >> 3, j = pos & 7;
        int n = (t / KT1) * 16 + (l & 15);
        int k = (t % KT1) * 32 + (l >> 4) * 8 + j;
        W1t[i] = (n < 400 && k < 376) ? f2bf(W1[k * 400 + n]) : (ushort_t)0;
    } else if (i < SZ1 + SZ2) {
        int i2 = i - SZ1;
        int t = i2 >> 9, pos = i2 & 511;
        int l = pos >> 3, j = pos & 7;
        int n = (t / KI2) * 16 + (l & 15);
        int k = (t % KI2) * 32 + (l >> 4) * 8 + j;
        W2t[i2] = (n < 300 && k < 400) ? f2bf(W2[k * 300 + n]) : (ushort_t)0;
    } else if (i < SZ1 + SZ2 + SZ3) {
        int i3 = i - SZ1 - SZ2;
        int t = i3 >> 9, pos = i3 & 511;
        int l = pos >> 3, j = pos & 7;
        int n = (t / KI3) * 16 + (l & 15);
        int k = (t % KI3) * 32 + (l >> 4) * 8 + j;
        float v = 0.f;
        if (k < 300) {
            if      (n < 17)  v = Wmu[k * 17 + n];
            else if (n < 34)  v = Wlv[k * 17 + (n - 17)];
            else if (n < 289) v = Wu[k * 255 + (n - 34)];
            else if (n < 544) v = Ww[k * 255 + (n - 289)];
            else if (n < 559) v = Wb[k * 15 + (n - 544)];
        }
        Wht[i3] = f2bf(v);
    } else {
        int j = i - SZ1 - SZ2 - SZ3;
        if (j < 480) {
            b1p[j] = (j < 400) ? b1[j] : 0.f;
        } else if (j < 800) {
            int n = j - 480;
            b2p[n] = (n < 300) ? b2[n] : 0.f;
        } else if (j < 1440) {
            int n = j - 800;
            float v = 0.f;
            if      (n < 17)  v = bmu[n];
            else if (n < 34)  v = blv[n - 17];
            else if (n < 289) v = bu[n - 34];
            else if (n < 544) v = bw[n - 289];
            else if (n < 559) v = bb[n - 544];
            bHp[n] = v;
        }
    }
}

// ---------------------------------------------------------------------------
// cvt_kernel: x fp32 row-major -> x' bf16 tile-order. One thread per 16-B unit.
// Unit U: tile = U>>6, l = U&63; row = (tile/KT1)*16 + (l&15); k0 = (tile%KT1)*32 + (l>>4)*8.
// k units are 8-aligned and 376 % 8 == 0, so units are fully valid or fully pad.
// ---------------------------------------------------------------------------
__global__ __launch_bounds__(256)
void cvt_kernel(const float* __restrict__ x, ushort_t* __restrict__ xt, int nUnits)
{
    int U = blockIdx.x * 256 + threadIdx.x;
    if (U >= nUnits) return;
    int t = U >> 6, l = U & 63;
    int rowblk = t / KT1, kblk = t - rowblk * KT1;
    long row = (long)rowblk * 16 + (l & 15);
    int k0 = kblk * 32 + (l >> 4) * 8;
    uint4 o = {0u, 0u, 0u, 0u};
    if (k0 + 8 <= 376) {
        const float4* p = reinterpret_cast<const float4*>(x + row * 376 + k0);
        float4 v0 = p[0], v1 = p[1];
        o.x = pack2(v0.x, v0.y); o.y = pack2(v0.z, v0.w);
        o.z = pack2(v1.x, v1.y); o.w = pack2(v1.z, v1.w);
    }
    reinterpret_cast<uint4*>(xt)[U] = o;   // unit order == linear 16-B order
}

// ---------------------------------------------------------------------------
// gemm_tile: C = act(A @ B^T + bias), all operands in MFMA-tile order except
// optionally C (row-major for the flow consumer).
// BM=128 (8 rowtiles), BN=160 (10 ntiles), BK=32; 256 thr = 4 waves.
// Staging via global_load_lds(16B) -> conflict-free ds_read_b128 frags.
//  kTA: A' row-stride in ktiles; kIters: # k-tiles (== B row-stride);
//  kTC: OUT_TILED ? C' row-stride in ktiles : row-major ldc.
// ---------------------------------------------------------------------------
template<bool RELU, bool OUT_TILED>
__global__ __launch_bounds__(256)
void gemm_tile(const ushort_t* __restrict__ A, const ushort_t* __restrict__ Bt,
               const float* __restrict__ bias, ushort_t* __restrict__ C,
               int kTA, int kIters, int kTC)
{
    __shared__ ushort_t As[8 * 512];
    __shared__ ushort_t Bs[10 * 512];
    const int tid = threadIdx.x;
    const int lane = tid & 63, wv = tid >> 6;
    const int q = lane >> 4, l16 = lane & 15;
    const int nb0 = blockIdx.x * 10;
    const int rowblk0 = blockIdx.y * 8;

    f32x4 acc[2][10];
    #pragma unroll
    for (int r = 0; r < 2; ++r)
        #pragma unroll
        for (int c = 0; c < 10; ++c)
            acc[r][c] = (f32x4){0.f, 0.f, 0.f, 0.f};

    for (int kt = 0; kt < kIters; ++kt) {
        // stage A: wave wv -> rowtiles 2wv, 2wv+1 (1024 B each, lds dest contiguous)
        #pragma unroll
        for (int i = 0; i < 2; ++i) {
            int t = wv * 2 + i;
            gl2lds16(A + (((size_t)(rowblk0 + t) * kTA + kt) << 9) + lane * 8,
                     &As[t << 9]);
        }
        // stage B: wave wv -> ntiles wv, wv+4, wv+8 (<10)
        #pragma unroll
        for (int t2 = 0; t2 < 3; ++t2) {
            int t = wv + t2 * 4;
            if (t < 10)
                gl2lds16(Bt + (((size_t)(nb0 + t) * kIters + kt) << 9) + lane * 8,
                         &Bs[t << 9]);
        }
        __syncthreads();

        bf16x8 a0 = __builtin_bit_cast(bf16x8,
            *reinterpret_cast<const uint4*>(&As[((wv * 2 + 0) << 9) + lane * 8]));
        bf16x8 a1 = __builtin_bit_cast(bf16x8,
            *reinterpret_cast<const uint4*>(&As[((wv * 2 + 1) << 9) + lane * 8]));
        #pragma unroll
        for (int c = 0; c < 10; ++c) {
            bf16x8 b = __builtin_bit_cast(bf16x8,
                *reinterpret_cast<const uint4*>(&Bs[(c << 9) + lane * 8]));
            acc[0][c] = __builtin_amdgcn_mfma_f32_16x16x32_bf16(a0, b, acc[0][c], 0, 0, 0);
            acc[1][c] = __builtin_amdgcn_mfma_f32_16x16x32_bf16(a1, b, acc[1][c], 0, 0, 0);
        }
        __syncthreads();
    }

    // epilogue: bias + act; C/D frag: col = l16, row = q*4+reg
    #pragma unroll
    for (int r = 0; r < 2; ++r) {
        int rowblk = rowblk0 + wv * 2 + r;
        #pragma unroll
        for (int c = 0; c < 10; ++c) {
            int n = (nb0 + c) * 16 + l16;
            float bv = bias[n];
            #pragma unroll
            for (int reg = 0; reg < 4; ++reg) {
                float v = acc[r][c][reg] + bv;
                if (RELU) v = fmaxf(v, 0.f);
                int mrow = q * 4 + reg;
                if (OUT_TILED) {
                    size_t off = (((size_t)rowblk * kTC + (n >> 5)) << 9)
                               + (size_t)(((n >> 3) & 3) * 16 + mrow) * 8 + (n & 7);
                    C[off] = f2bf(v);
                } else {
                    long m = (long)rowblk * 16 + mrow;
                    C[m * (long)kTC + n] = f2bf(v);
                }
            }
        }
    }
}

// ---------------------------------------------------------------------------
// flow_kernel: one THREAD per row; block = 128 rows. heads row-major ld 640:
//  [0:17) mu, [17:34) lv, [34:289) u, [289:544) w, [544:559) b
// Transposed LDS staging (stride 129) keeps both phases conflict-free.
// ---------------------------------------------------------------------------
#define FR 128

__global__ __launch_bounds__(FR)
void flow_kernel(const ushort_t* __restrict__ heads, const float* __restrict__ eps,
                 float* __restrict__ out, int rowBase, int B)
{
    __shared__ float lu[17 * (FR + 1)];
    __shared__ float lw[17 * (FR + 1)];
    __shared__ float le[17 * (FR + 1)];
    __shared__ float lb[FR];
    const int tid = threadIdx.x;
    const long row0 = (long)blockIdx.x * FR;
    const ushort_t* hbase = heads + row0 * LDC3;

    for (int idx = tid; idx < FR * 17; idx += FR) {
        int r = idx / 17, i = idx - r * 17;
        lu[i * (FR + 1) + r] = bf2f(hbase[(long)r * LDC3 + i]);
        lw[i * (FR + 1) + r] = bf2f(hbase[(long)r * LDC3 + 17 + i]);
        le[i * (FR + 1) + r] = eps[row0 * 17 + idx];
    }
    __syncthreads();

    float z[17];
    float lp = 0.f;
    #pragma unroll
    for (int i = 0; i < 17; ++i) {
        float mu = fast_tanh(lu[i * (FR + 1) + tid]);
        float lv = fast_tanh(lw[i * (FR + 1) + tid]);
        float ep = le[i * (FR + 1) + tid];
        z[i] = mu + __expf(lv) * ep;
        lp += -0.5f * ep * ep - lv - 0.918938533f;
    }

    float ldj = 0.f;
    for (int k = 0; k < 15; ++k) {
        __syncthreads();
        for (int idx = tid; idx < FR * 17; idx += FR) {
            int r = idx / 17, i = idx - r * 17;
            long rb = (long)r * LDC3;
            lu[i * (FR + 1) + r] = bf2f(hbase[rb + 34 + k * 17 + i]);
            lw[i * (FR + 1) + r] = bf2f(hbase[rb + 289 + k * 17 + i]);
        }
        lb[tid] = bf2f(hbase[(long)tid * LDC3 + 544 + k]);
        __syncthreads();

        float u[17], w[17];
        float uw = 0.f, w2 = 0.f, wz = 0.f;
        #pragma unroll
        for (int i = 0; i < 17; ++i) {
            u[i] = lu[i * (FR + 1) + tid];
            w[i] = lw[i * (FR + 1) + tid];
            uw += w[i] * u[i];
            w2 += w[i] * w[i];
            wz += w[i] * z[i];
        }
        float sp = (uw > 15.f) ? uw : __logf(1.f + __expf(uw));
        float m = sp - 1.f;                          // -1 + softplus(w.u)
        float coef = (m - uw) / fmaxf(w2, 1e-20f);
        float t = fast_tanh(wz + lb[tid]);
        #pragma unroll
        for (int i = 0; i < 17; ++i)
            z[i] += (u[i] + coef * w[i]) * t;
        float psi = m * (1.f - t * t);               // psi^T u_hat == m analytically
        ldj += __logf(fmaxf(fabsf(1.f + psi), 1e-30f));
    }

    const long g = rowBase + row0 + tid;
    #pragma unroll
    for (int i = 0; i < 17; ++i) out[g * 17 + i] = z[i];
    float lpf = lp - ldj;
    out[(long)B * 17 + g] = __expf(lpf);
    out[(long)B * 18 + g] = lpf;
}

// ---------------------------------------------------------------------------
extern "C" void kernel_launch(void* const* d_in, const int* in_sizes, int n_in,
                              void* d_out, int out_size, void* d_ws, size_t ws_size,
                              hipStream_t stream)
{
    const float* x   = (const float*)d_in[0];
    const float* eps = (const float*)d_in[1];
    float* out = (float*)d_out;

    // ws layout per chunk of Mc rows:
    //   region1 (Mc*640 us): h1' tiled (uses Mc*480), later heads row-major 640
    //   region2 (Mc*384 us): x' tiled (Mc*384), later h2' tiled (Mc*320)
    //   weights: W1t | W2t | Wht | b1p(480 f32) | b2p(320) | bHp(640)
    const size_t wUS = (size_t)SZ1 + SZ2 + SZ3;
    const size_t fixedBytes = wUS * 2 + (480 + 320 + 640) * 4;
    int Mc = 2048;
    {
        const int cand[6] = {65536, 32768, 16384, 8192, 4096, 2048};
        for (int i = 0; i < 6; ++i) {
            size_t req = (size_t)cand[i] * 2048 + fixedBytes;
            if (req <= ws_size) { Mc = cand[i]; break; }
        }
    }

    ushort_t* region1 = (ushort_t*)d_ws;
    ushort_t* region2 = region1 + (size_t)Mc * 640;
    ushort_t* W1t = region2 + (size_t)Mc * 384;
    ushort_t* W2t = W1t + SZ1;
    ushort_t* Wht = W2t + SZ2;
    float* b1p = (float*)(Wht + SZ3);
    float* b2p = b1p + 480;
    float* bHp = b2p + 320;

    const int packN = SZ1 + SZ2 + SZ3 + 1440;
    pack_kernel<<<(packN + 255) / 256, 256, 0, stream>>>(
        (const float*)d_in[2],  (const float*)d_in[4],
        (const float*)d_in[6],  (const float*)d_in[8],
        (const float*)d_in[10], (const float*)d_in[12], (const float*)d_in[14],
        (const float*)d_in[3],  (const float*)d_in[5],
        (const float*)d_in[7],  (const float*)d_in[9],
        (const float*)d_in[11], (const float*)d_in[13], (const float*)d_in[15],
        W1t, W2t, Wht, b1p, b2p, bHp);

    const int nChunks = B_ROWS / Mc;
    const int nUnits = Mc * 48;                     // (Mc/16)*KT1*64
    for (int c = 0; c < nChunks; ++c) {
        const float* xc = x + (size_t)c * Mc * 376;
        // C0: x -> x' (bf16, tile order) in region2
        cvt_kernel<<<(nUnits + 255) / 256, 256, 0, stream>>>(xc, region2, nUnits);
        // K1: h1' = relu(x' @ W1^T + b1)   M=Mc K=384 N=480(pad) -> tiled, stride 15
        gemm_tile<true, true><<<dim3(3, Mc / 128), 256, 0, stream>>>(
            region2, W1t, b1p, region1, KT1, KT1, KTC1);
        // K2: h2' = relu(h1' @ W2^T + b2)  M=Mc K=416 N=320 -> tiled, stride 10
        gemm_tile<true, true><<<dim3(2, Mc / 128), 256, 0, stream>>>(
            region1, W2t, b2p, region2, KTC1, KI2, KTC2);
        // K3: heads = h2' @ Wh^T + bH      M=Mc K=320 N=640(pad) -> row-major 640
        gemm_tile<false, false><<<dim3(4, Mc / 128), 256, 0, stream>>>(
            region2, Wht, bHp, region1, KTC2, KI3, LDC3);
        // K4: planar flow + log-prob
        flow_kernel<<<Mc / FR, FR, 0, stream>>>(region1, eps + (size_t)c * Mc * 17,
                                                out, c * Mc, B_ROWS);
    }
}